// Round 5
// baseline (270.162 us; speedup 1.0000x reference)
//
#include <hip/hip_runtime.h>

// DynamicFC: out[b,o,h,w] = sum_i w[b,o,i] * x[b,i,h,w] + bias[b,o]
// Batched GEMM per b: M=Cout=512, N=HW=784, K=Cin=512, fp32 in/out.
// R7 vs R6 (R6 post-mortem: VGPR=100 -> WRITE_SET hoisted to region top, so
// its vmcnt wait landed BEFORE the MFMA block; plus __syncthreads' mandatory
// vmcnt(0) drain caps in-flight depth at one region. And my B-write remap was
// a 14-way bank conflict: SQ_LDS_BANK_CONFLICT 5.5M -> 17M):
//  - B staging mapping reverted to R3 form (kg=tid&7, ng=tid>>3): 16 banks,
//    4-way write aliasing (~free per m136).
//  - Raw s_barrier + explicit "s_waitcnt lgkmcnt(0)" (T4 discipline): no
//    vmcnt(0) drain at barriers -> global loads stay in flight across them.
//    The only vmcnt waits are the compiler's counted, dependency-driven ones
//    at WRITE_SET (loads retire in order: waiting on set B leaves set A's 8
//    loads flying). In-flight window = 2 full compute phases vs ~500cy L2.
//  - sched_barrier(0) BETWEEN COMPUTE and WRITE_SET (and after LOAD_SET) so
//    the scheduler cannot hoist the write (and its vmcnt wait) above the
//    MFMA block — R6's failure mode.
//  - LDS visibility: ds_writes drained with lgkmcnt(0) before each barrier
//    (exactly what __syncthreads does for LDS); reads can't hoist past the
//    asm memory clobber. Global loads crossing barriers touch regs only.

#define CIN  512
#define COUT 512
#define HW   784      // 28*28 = 7*112
#define BM   128
#define BN   112
#define BK   32
#define LSTR 40       // 32 + 8 pad bf16 (80B row)

typedef __bf16 bf16_t;
typedef __bf16 bf16x8 __attribute__((ext_vector_type(8)));
typedef __bf16 bf16x4 __attribute__((ext_vector_type(4)));
typedef float  f32x4  __attribute__((ext_vector_type(4)));

__device__ __forceinline__ bf16x8 pack8(f32x4 a, f32x4 b) {
    bf16x8 r;
    r[0] = (bf16_t)a[0]; r[1] = (bf16_t)a[1];
    r[2] = (bf16_t)a[2]; r[3] = (bf16_t)a[3];
    r[4] = (bf16_t)b[0]; r[5] = (bf16_t)b[1];
    r[6] = (bf16_t)b[2]; r[7] = (bf16_t)b[3];
    return r;
}

// lgkmcnt(0) (LDS write visibility) + raw barrier. NO vmcnt drain: global
// loads stay in flight across the barrier. sched_barrier keeps the machine
// scheduler from migrating memory ops around the barrier cluster.
#define BARRIER() do {                                        \
        __builtin_amdgcn_sched_barrier(0);                    \
        asm volatile("s_waitcnt lgkmcnt(0)" ::: "memory");    \
        __builtin_amdgcn_s_barrier();                         \
        __builtin_amdgcn_sched_barrier(0);                    \
    } while (0)

__global__ __launch_bounds__(256, 2) void dynfc_kernel(
    const float* __restrict__ x,     // [64][512][784]
    const float* __restrict__ w,     // [64][512][512]
    const float* __restrict__ bias,  // [64][512]
    float* __restrict__ out)         // [64][512][784]
{
    __shared__ bf16_t Asm[2][BM * LSTR];   // 2 x 10 KB
    __shared__ bf16_t Bsm[2][BN * LSTR];   // 2 x 8.75 KB  (total 38.4 KB)
    __shared__ float  bias_sm[BM];

    // XCD swizzle: whole batches per XCD so W+X re-reads hit that XCD's L2.
    const int bid   = blockIdx.x;        // 0..1791
    const int xcd   = bid & 7;
    const int j     = bid >> 3;          // 0..223
    const int batch = xcd + 8 * (j / 28);
    const int trem  = j % 28;            // 4 m-tiles * 7 n-tiles
    const int tm    = trem / 7;
    const int tn    = trem % 7;
    const int m0    = tm * BM;
    const int n0    = tn * BN;

    const int tid  = threadIdx.x;
    const int lane = tid & 63;
    const int wid  = tid >> 6;
    const int wm   = wid * 32;           // wave's 32-row slice
    const int l15  = lane & 15;
    const int quad = lane >> 4;

    const float* xb = x + (size_t)batch * CIN * HW;
    const float* wb = w + (size_t)batch * COUT * CIN;

    if (tid < 32) {
        f32x4 bv = *(const f32x4*)(bias + batch * COUT + m0 + tid * 4);
        *(f32x4*)&bias_sm[tid * 4] = bv;
    }

    // A staging: thread -> (row ar of 128, k-half ah of {0,16}); 16 fp32.
    const int ar = tid >> 1;
    const int ah = (tid & 1) * 16;
    // B staging (R3 mapping): kg = tid&7 (k-group), ng = tid>>3 (col-group).
    // Write banks = (16ng + 20nn + 2kg) mod 32 -> 16 banks, 4-way (~free).
    const int  kg      = tid & 7;        // 0..7
    const int  ng      = tid >> 3;       // 0..31
    const bool bactive = (ng < 28);      // 28*4 = 112 cols exactly

    const float* asrc = wb + (size_t)(m0 + ar) * CIN + ah;
    const float* bsrc = xb + (size_t)(kg * 4) * HW + n0 + ng * 4;

    f32x4 aA[4], bA[4], aB[4], bB[4];    // two staging register sets

#define LOAD_SET(aR, bR, t) do {                                              \
        const float* ap_ = asrc + (t) * BK;                                   \
        aR[0] = *(const f32x4*)(ap_);      aR[1] = *(const f32x4*)(ap_ + 4);  \
        aR[2] = *(const f32x4*)(ap_ + 8);  aR[3] = *(const f32x4*)(ap_ + 12); \
        if (bactive) {                                                        \
            const float* bp_ = bsrc + (size_t)((t) * BK) * HW;                \
            bR[0] = *(const f32x4*)(bp_);                                     \
            bR[1] = *(const f32x4*)(bp_ + HW);                                \
            bR[2] = *(const f32x4*)(bp_ + 2 * HW);                            \
            bR[3] = *(const f32x4*)(bp_ + 3 * HW);                            \
        }                                                                     \
    } while (0)

#define WRITE_SET(aR, bR, s) do {                                             \
        bf16_t* Ab_ = &Asm[s][0];                                             \
        bf16_t* Bb_ = &Bsm[s][0];                                             \
        *(bf16x8*)&Ab_[ar * LSTR + ah]     = pack8(aR[0], aR[1]);             \
        *(bf16x8*)&Ab_[ar * LSTR + ah + 8] = pack8(aR[2], aR[3]);             \
        if (bactive) {                                                        \
            _Pragma("unroll")                                                 \
            for (int nn = 0; nn < 4; nn++) {                                  \
                bf16x4 c_;                                                    \
                c_[0] = (bf16_t)bR[0][nn]; c_[1] = (bf16_t)bR[1][nn];         \
                c_[2] = (bf16_t)bR[2][nn]; c_[3] = (bf16_t)bR[3][nn];         \
                *(bf16x4*)&Bb_[(ng * 4 + nn) * LSTR + kg * 4] = c_;           \
            }                                                                 \
        }                                                                     \
    } while (0)

#define COMPUTE(s) do {                                                       \
        const bf16_t* Ab_ = &Asm[s][0];                                       \
        const bf16_t* Bb_ = &Bsm[s][0];                                       \
        bf16x8 af_[2], bf_[7];                                                \
        _Pragma("unroll")                                                     \
        for (int i = 0; i < 2; i++)                                           \
            af_[i] = *(const bf16x8*)&Ab_[(wm + i * 16 + l15) * LSTR + quad * 8]; \
        _Pragma("unroll")                                                     \
        for (int j2 = 0; j2 < 7; j2++)                                        \
            bf_[j2] = *(const bf16x8*)&Bb_[(j2 * 16 + l15) * LSTR + quad * 8];\
        __builtin_amdgcn_s_setprio(1);                                        \
        _Pragma("unroll")                                                     \
        for (int i = 0; i < 2; i++)                                           \
            _Pragma("unroll")                                                 \
            for (int j2 = 0; j2 < 7; j2++)                                    \
                acc[i][j2] = __builtin_amdgcn_mfma_f32_16x16x32_bf16(af_[i], bf_[j2], acc[i][j2], 0, 0, 0); \
        __builtin_amdgcn_s_setprio(0);                                        \
    } while (0)

    f32x4 acc[2][7] = {};

    // ---- prologue: tile0 -> buf0 (via setA); tile1 -> setB ----
    LOAD_SET(aA, bA, 0);
    WRITE_SET(aA, bA, 0);     // compiler emits counted vmcnt for aA/bA here
    LOAD_SET(aB, bB, 1);
    BARRIER();

    // tile k lives in buf[k&1] and register set (k&1 ? B : A)
    #pragma unroll
    for (int tt = 0; tt < 16; tt += 2) {
        // ---- even sub-iter: compute tile tt from buf0 ----
        if (tt + 2 < 16) LOAD_SET(aA, bA, tt + 2);
        __builtin_amdgcn_sched_barrier(0);   // loads pinned above compute
        COMPUTE(0);
        __builtin_amdgcn_sched_barrier(0);   // write (and its vmcnt wait)
        WRITE_SET(aB, bB, 1);                //   pinned BELOW compute
        BARRIER();

        // ---- odd sub-iter: compute tile tt+1 from buf1 ----
        if (tt + 3 < 16) LOAD_SET(aB, bB, tt + 3);
        __builtin_amdgcn_sched_barrier(0);
        COMPUTE(1);
        __builtin_amdgcn_sched_barrier(0);
        if (tt + 2 < 16) WRITE_SET(aA, bA, 0);
        BARRIER();
    }

#undef LOAD_SET
#undef WRITE_SET
#undef COMPUTE

    // ---- epilogue: add bias, plain store (7*112 == 784, no guard) ----
    // C/D layout: col = lane&15, row = quad*4 + r
    float* ob = out + (size_t)batch * COUT * HW;
    #pragma unroll
    for (int j2 = 0; j2 < 7; j2++) {
        const int n = n0 + j2 * 16 + l15;
        #pragma unroll
        for (int i = 0; i < 2; i++) {
            #pragma unroll
            for (int r = 0; r < 4; r++) {
                const int m = wm + i * 16 + quad * 4 + r;
                ob[(size_t)(m0 + m) * HW + n] = acc[i][j2][r] + bias_sm[m];
            }
        }
    }
}

extern "C" void kernel_launch(void* const* d_in, const int* in_sizes, int n_in,
                              void* d_out, int out_size, void* d_ws, size_t ws_size,
                              hipStream_t stream) {
    (void)in_sizes; (void)n_in; (void)d_ws; (void)ws_size; (void)out_size;
    const float* x    = (const float*)d_in[0];
    const float* w    = (const float*)d_in[1];
    const float* bias = (const float*)d_in[2];
    float* out        = (float*)d_out;

    dim3 grid(64 * 4 * 7);   // 64 batches * 4 m-tiles * 7 n-tiles
    dim3 block(256);
    dynfc_kernel<<<grid, block, 0, stream>>>(x, w, bias, out);
}